// Round 4
// baseline (384.658 us; speedup 1.0000x reference)
//
#include <hip/hip_runtime.h>
#include <stdint.h>

#define SW 1024
#define NB 128                   // 128 bands x 8 rows
#define N_HITS (1 << 24)
#define B1 1024                  // blocks for count/scatter
#define HPB (N_HITS / B1)        // 16384 hits per block
#define RND (HPB / 1024)         // 16 rounds (256 thr * 4)
#define CHUNK 65536              // hits per accumulation chunk
#define MAXCH (NB + N_HITS / CHUNK)   // 128 + 256 = 384
#define HISTW (8 * 1024)         // 8 rows x 1024 cols = 32 KB

// ws layout (u32 words)
#define OFS_CNT   0u
#define OFS_BASE  (OFS_CNT + (uint32_t)B1 * NB)      // 131072
#define OFS_TOTAL (OFS_BASE + (uint32_t)B1 * NB)     // 262144
#define OFS_BOFF  (OFS_TOTAL + NB)                   // 262272
#define OFS_CBASE (OFS_BOFF + NB + 1)                // 262401
#define OFS_PAIRS 262532u                            // mult of 4 -> 16B aligned
#define PAIR_CAP  ((uint32_t)N_HITS + 256u)          // + band-padding slack
#define OFS_PART  (OFS_PAIRS + 2u * PAIR_CAP)        // 33817476 (mult of 4)
#define WS_WORDS  (OFS_PART + (uint32_t)MAXCH * HISTW)
#define WS_BYTES  ((size_t)WS_WORDS * 4u)            // ~147.85 MB

#define INV_D 0.005859375f       // 6/1024, exact

__device__ __forceinline__ uint32_t pix_of(float x, float y) {
    float fx = floorf((x + 3.0f) / INV_D);
    float fy = floorf((y + 3.0f) / INV_D);
    if (fx >= 0.0f && fx < 1024.0f && fy >= 0.0f && fy < 1024.0f) {
        return ((uint32_t)(int)fy << 10) | (uint32_t)(int)fx;
    }
    return 0xFFFFFFFFu;
}

// ---- pass 1a: per-(block,band) counts from y only ----------------------
__global__ __launch_bounds__(256) void k_count(const float4* __restrict__ y4,
                                               uint32_t* __restrict__ cnt) {
    __shared__ uint32_t lcnt[4 * NB];   // per-wave counters to cut contention
    int tid = threadIdx.x, b = blockIdx.x;
    int wave = tid >> 6;
    lcnt[tid] = 0;
    lcnt[tid + 256] = 0;
    __syncthreads();
    int base4 = b * (HPB / 4);
#pragma unroll
    for (int r = 0; r < RND; ++r) {
        float4 yv = y4[base4 + r * 256 + tid];
        float ys[4] = {yv.x, yv.y, yv.z, yv.w};
#pragma unroll
        for (int j = 0; j < 4; ++j) {
            float fy = floorf((ys[j] + 3.0f) / INV_D);
            if (fy >= 0.0f && fy < 1024.0f) {
                atomicAdd(&lcnt[wave * NB + ((int)fy >> 3)], 1u);
            }
        }
    }
    __syncthreads();
    if (tid < NB)
        cnt[b * NB + tid] = lcnt[tid] + lcnt[NB + tid] + lcnt[2 * NB + tid] + lcnt[3 * NB + tid];
}

// ---- pass 1b: per-band exclusive scan over blocks ----------------------
__global__ __launch_bounds__(256) void k_scan_blocks(const uint32_t* __restrict__ cnt,
                                                     uint32_t* __restrict__ base,
                                                     uint32_t* __restrict__ total) {
    __shared__ uint32_t s[256];
    __shared__ uint32_t carry;
    int t = blockIdx.x, tid = threadIdx.x;
    if (tid == 0) carry = 0;
    __syncthreads();
    for (int r = 0; r < B1 / 256; ++r) {
        int b = r * 256 + tid;
        uint32_t v = cnt[b * NB + t];
        s[tid] = v;
        __syncthreads();
        for (int off = 1; off < 256; off <<= 1) {
            uint32_t add = (tid >= off) ? s[tid - off] : 0u;
            __syncthreads();
            s[tid] += add;
            __syncthreads();
        }
        uint32_t incl = s[tid];
        uint32_t c = carry;
        base[b * NB + t] = c + incl - v;
        __syncthreads();
        if (tid == 255) carry = c + incl;
        __syncthreads();
    }
    if (tid == 0) total[t] = carry;
}

// ---- pass 1b2: band offsets (padded to 2-pair alignment) + chunk bases -
__global__ __launch_bounds__(64) void k_scan_bands(const uint32_t* __restrict__ total,
                                                   uint32_t* __restrict__ boff,
                                                   uint32_t* __restrict__ cbase) {
    if (threadIdx.x == 0 && blockIdx.x == 0) {
        uint32_t acc = 0, cacc = 0;
        for (int i = 0; i < NB; ++i) {
            boff[i] = acc;
            cbase[i] = cacc;
            uint32_t v = total[i];
            acc += v;
            acc = (acc + 1u) & ~1u;          // keep band starts 16B-aligned
            uint32_t cc = (v + CHUNK - 1) / CHUNK;
            cacc += (cc == 0) ? 1u : cc;
        }
        boff[NB] = acc;
        cbase[NB] = cacc;
    }
}

// ---- pass 1c: scatter (pixel,value) pairs into per-band lists ----------
__global__ __launch_bounds__(256) void k_scatter(const float4* __restrict__ x4,
                                                 const float4* __restrict__ y4,
                                                 const float4* __restrict__ v4,
                                                 const uint32_t* __restrict__ base,
                                                 const uint32_t* __restrict__ boff,
                                                 uint2* __restrict__ pairs) {
    __shared__ uint32_t lcur[NB];
    int tid = threadIdx.x, b = blockIdx.x;
    if (tid < NB) lcur[tid] = boff[tid] + base[b * NB + tid];
    __syncthreads();
    int base4 = b * (HPB / 4);
#pragma unroll
    for (int r = 0; r < RND; ++r) {
        float4 xv = x4[base4 + r * 256 + tid];
        float4 yv = y4[base4 + r * 256 + tid];
        float4 vv = v4[base4 + r * 256 + tid];
        float xs[4] = {xv.x, xv.y, xv.z, xv.w};
        float ys[4] = {yv.x, yv.y, yv.z, yv.w};
        float vs[4] = {vv.x, vv.y, vv.z, vv.w};
#pragma unroll
        for (int j = 0; j < 4; ++j) {
            float fy = floorf((ys[j] + 3.0f) / INV_D);
            if (fy >= 0.0f && fy < 1024.0f) {
                int yi = (int)fy;
                float fx = floorf((xs[j] + 3.0f) / INV_D);
                bool xok = (fx >= 0.0f && fx < 1024.0f);
                uint32_t p = ((uint32_t)yi << 10) | (xok ? (uint32_t)(int)fx : 0u);
                float val = xok ? vs[j] : 0.0f;
                uint32_t slot = atomicAdd(&lcur[yi >> 3], 1u);
                pairs[slot] = make_uint2(p, __float_as_uint(val));
            }
        }
    }
}

// ---- pass 2: per-chunk LDS band histogram (8x1024, 32 KB) --------------
__global__ __launch_bounds__(512) void k_accum(const uint2* __restrict__ pairs,
                                               const uint32_t* __restrict__ boff,
                                               const uint32_t* __restrict__ total,
                                               const uint32_t* __restrict__ cbase,
                                               float* __restrict__ partials) {
    __shared__ float hist[HISTW];
    int c = blockIdx.x, tid = threadIdx.x;
    uint32_t nch = cbase[NB];
    if ((uint32_t)c >= nch) return;
    int lo = 0, hi = NB - 1;
    while (lo < hi) {
        int mid = (lo + hi + 1) >> 1;
        if (cbase[mid] <= (uint32_t)c) lo = mid; else hi = mid - 1;
    }
    int t = lo;
    uint32_t k = (uint32_t)c - cbase[t];
    uint32_t st = boff[t] + k * (uint32_t)CHUNK;       // even (boff even, CHUNK even)
    uint32_t en = boff[t] + total[t];
    uint32_t en2 = st + (uint32_t)CHUNK;
    if (en2 < en) en = en2;
    for (int i = tid; i < HISTW; i += 512) hist[i] = 0.0f;
    __syncthreads();
    uint32_t npairs = (en > st) ? (en - st) : 0u;
    uint32_t nv = npairs >> 1;                          // uint4 = 2 pairs
    const uint4* p4 = (const uint4*)(pairs + st);
    for (uint32_t i = (uint32_t)tid; i < nv; i += 512) {
        uint4 pr = p4[i];
        atomicAdd(&hist[((pr.x >> 10) & 7u) * 1024 + (pr.x & 1023u)], __uint_as_float(pr.y));
        atomicAdd(&hist[((pr.z >> 10) & 7u) * 1024 + (pr.z & 1023u)], __uint_as_float(pr.w));
    }
    if ((npairs & 1u) && tid == 0) {
        uint2 pr = pairs[en - 1];
        atomicAdd(&hist[((pr.x >> 10) & 7u) * 1024 + (pr.x & 1023u)], __uint_as_float(pr.y));
    }
    __syncthreads();
    float4* dst = (float4*)(partials + (size_t)c * HISTW);
    const float4* src = (const float4*)hist;
    for (int i = tid; i < HISTW / 4; i += 512) dst[i] = src[i];
}

// ---- pass 3: reduce partials, write final image (every pixel once) -----
__global__ __launch_bounds__(256) void k_reduce(const float* __restrict__ partials,
                                                const uint32_t* __restrict__ cbase,
                                                float* __restrict__ out) {
    int t = blockIdx.x, tid = threadIdx.x;
    uint32_t c0 = cbase[t], c1 = cbase[t + 1];
    float4* o4 = (float4*)(out + (size_t)t * HISTW);
    for (int i = tid; i < HISTW / 4; i += 256) {
        float4 s = make_float4(0.f, 0.f, 0.f, 0.f);
        for (uint32_t c = c0; c < c1; ++c) {
            float4 p = ((const float4*)(partials + (size_t)c * HISTW))[i];
            s.x += p.x; s.y += p.y; s.z += p.z; s.w += p.w;
        }
        o4[i] = s;
    }
}

// ---- fallback: direct-atomic version (known-correct) -------------------
__global__ __launch_bounds__(256) void k_naive(const float4* __restrict__ x4,
                                               const float4* __restrict__ y4,
                                               const float4* __restrict__ v4,
                                               float* __restrict__ out,
                                               int n_chunks) {
    int stride = gridDim.x * blockDim.x;
    for (int i = blockIdx.x * blockDim.x + threadIdx.x; i < n_chunks; i += stride) {
        float4 xv = x4[i];
        float4 yv = y4[i];
        float4 vv = v4[i];
        float xs[4] = {xv.x, xv.y, xv.z, xv.w};
        float ys[4] = {yv.x, yv.y, yv.z, yv.w};
        float vs[4] = {vv.x, vv.y, vv.z, vv.w};
#pragma unroll
        for (int j = 0; j < 4; ++j) {
            uint32_t p = pix_of(xs[j], ys[j]);
            if (p != 0xFFFFFFFFu) atomicAdd(&out[(p >> 10) * SW + (p & 1023u)], vs[j]);
        }
    }
}

extern "C" void kernel_launch(void* const* d_in, const int* in_sizes, int n_in,
                              void* d_out, int out_size, void* d_ws, size_t ws_size,
                              hipStream_t stream) {
    const float* x = (const float*)d_in[0];
    const float* y = (const float*)d_in[1];
    const float* v = (const float*)d_in[2];
    float* out = (float*)d_out;
    int n = in_sizes[0];

    if (n == N_HITS && ws_size >= WS_BYTES) {
        uint32_t* w = (uint32_t*)d_ws;
        uint32_t* cnt   = w + OFS_CNT;
        uint32_t* base  = w + OFS_BASE;
        uint32_t* total = w + OFS_TOTAL;
        uint32_t* boff  = w + OFS_BOFF;
        uint32_t* cbase = w + OFS_CBASE;
        uint2*    pairs = (uint2*)(w + OFS_PAIRS);
        float*    parts = (float*)(w + OFS_PART);

        k_count<<<B1, 256, 0, stream>>>((const float4*)y, cnt);
        k_scan_blocks<<<NB, 256, 0, stream>>>(cnt, base, total);
        k_scan_bands<<<1, 64, 0, stream>>>(total, boff, cbase);
        k_scatter<<<B1, 256, 0, stream>>>((const float4*)x, (const float4*)y,
                                          (const float4*)v, base, boff, pairs);
        k_accum<<<MAXCH, 512, 0, stream>>>(pairs, boff, total, cbase, parts);
        k_reduce<<<NB, 256, 0, stream>>>(parts, cbase, out);
    } else {
        hipMemsetAsync(out, 0, (size_t)out_size * sizeof(float), stream);
        k_naive<<<4096, 256, 0, stream>>>((const float4*)x, (const float4*)y,
                                          (const float4*)v, out, n / 4);
    }
}

// Round 5
// 277.190 us; speedup vs baseline: 1.3877x; 1.3877x over previous
//
#include <hip/hip_runtime.h>
#include <stdint.h>

#define SW 1024
#define NB 128                   // 128 bands x 8 rows
#define N_HITS (1 << 24)
#define B1 1024                  // blocks for count/scatter
#define HPB (N_HITS / B1)        // 16384 hits per block
#define RND (HPB / 1024)         // 16 rounds (256 thr * 4) for k_count
#define SB 4096                  // hits per scatter sub-batch
#define SBF4 (SB / 4)            // 1024 float4 per sub-batch
#define NSB (HPB / SB)           // 4 sub-batches
#define CHUNK 65536              // hits per accumulation chunk
#define MAXCH (NB + N_HITS / CHUNK)   // 128 + 256 = 384
#define HISTW (8 * 1024)         // 8 rows x 1024 cols = 32 KB

// ws layout (u32 words) -- identical to round 4 (147.85 MB, proven to fit)
#define OFS_CNT   0u
#define OFS_BASE  (OFS_CNT + (uint32_t)B1 * NB)      // 131072
#define OFS_TOTAL (OFS_BASE + (uint32_t)B1 * NB)     // 262144
#define OFS_BOFF  (OFS_TOTAL + NB)                   // 262272
#define OFS_CBASE (OFS_BOFF + NB + 1)                // 262401
#define OFS_PAIRS 262532u                            // mult of 4 -> 16B aligned
#define PAIR_CAP  ((uint32_t)N_HITS + 256u)
#define OFS_PART  (OFS_PAIRS + 2u * PAIR_CAP)
#define WS_WORDS  (OFS_PART + (uint32_t)MAXCH * HISTW)
#define WS_BYTES  ((size_t)WS_WORDS * 4u)

#define INV_D 0.005859375f       // 6/1024, exact

__device__ __forceinline__ uint32_t pix_of(float x, float y) {
    float fx = floorf((x + 3.0f) / INV_D);
    float fy = floorf((y + 3.0f) / INV_D);
    if (fx >= 0.0f && fx < 1024.0f && fy >= 0.0f && fy < 1024.0f) {
        return ((uint32_t)(int)fy << 10) | (uint32_t)(int)fx;
    }
    return 0xFFFFFFFFu;
}

// ---- pass 1a: per-(block,band) counts from y only ----------------------
__global__ __launch_bounds__(256) void k_count(const float4* __restrict__ y4,
                                               uint32_t* __restrict__ cnt) {
    __shared__ uint32_t lcnt[4 * NB];
    int tid = threadIdx.x, b = blockIdx.x;
    int wave = tid >> 6;
    lcnt[tid] = 0;
    lcnt[tid + 256] = 0;
    __syncthreads();
    int base4 = b * (HPB / 4);
#pragma unroll
    for (int r = 0; r < RND; ++r) {
        float4 yv = y4[base4 + r * 256 + tid];
        float ys[4] = {yv.x, yv.y, yv.z, yv.w};
#pragma unroll
        for (int j = 0; j < 4; ++j) {
            float fy = floorf((ys[j] + 3.0f) / INV_D);
            if (fy >= 0.0f && fy < 1024.0f) {
                atomicAdd(&lcnt[wave * NB + ((int)fy >> 3)], 1u);
            }
        }
    }
    __syncthreads();
    if (tid < NB)
        cnt[b * NB + tid] = lcnt[tid] + lcnt[NB + tid] + lcnt[2 * NB + tid] + lcnt[3 * NB + tid];
}

// ---- pass 1b: per-band exclusive scan over blocks ----------------------
__global__ __launch_bounds__(256) void k_scan_blocks(const uint32_t* __restrict__ cnt,
                                                     uint32_t* __restrict__ base,
                                                     uint32_t* __restrict__ total) {
    __shared__ uint32_t s[256];
    __shared__ uint32_t carry;
    int t = blockIdx.x, tid = threadIdx.x;
    if (tid == 0) carry = 0;
    __syncthreads();
    for (int r = 0; r < B1 / 256; ++r) {
        int b = r * 256 + tid;
        uint32_t v = cnt[b * NB + t];
        s[tid] = v;
        __syncthreads();
        for (int off = 1; off < 256; off <<= 1) {
            uint32_t add = (tid >= off) ? s[tid - off] : 0u;
            __syncthreads();
            s[tid] += add;
            __syncthreads();
        }
        uint32_t incl = s[tid];
        uint32_t c = carry;
        base[b * NB + t] = c + incl - v;
        __syncthreads();
        if (tid == 255) carry = c + incl;
        __syncthreads();
    }
    if (tid == 0) total[t] = carry;
}

// ---- pass 1b2: band offsets (16B-aligned starts) + chunk bases ---------
__global__ __launch_bounds__(64) void k_scan_bands(const uint32_t* __restrict__ total,
                                                   uint32_t* __restrict__ boff,
                                                   uint32_t* __restrict__ cbase) {
    if (threadIdx.x == 0 && blockIdx.x == 0) {
        uint32_t acc = 0, cacc = 0;
        for (int i = 0; i < NB; ++i) {
            boff[i] = acc;
            cbase[i] = cacc;
            uint32_t v = total[i];
            acc += v;
            acc = (acc + 1u) & ~1u;
            uint32_t cc = (v + CHUNK - 1) / CHUNK;
            cacc += (cc == 0) ? 1u : cc;
        }
        boff[NB] = acc;
        cbase[NB] = cacc;
    }
}

// ---- pass 1c: LDS counting-sort scatter --------------------------------
// Per 4096-hit sub-batch: band-count -> scan -> place into LDS sorted
// buffer -> linear copy-out (piecewise-contiguous global stores so L2
// write-combines full lines; fixes the 2x WRITE_SIZE amplification).
__global__ __launch_bounds__(512) void k_scatter(const float4* __restrict__ x4,
                                                 const float4* __restrict__ y4,
                                                 const float4* __restrict__ v4,
                                                 const uint32_t* __restrict__ base,
                                                 const uint32_t* __restrict__ boff,
                                                 uint2* __restrict__ pairs) {
    __shared__ uint32_t bh[NB];      // sub-batch band counts
    __shared__ uint32_t ps[NB];      // scan scratch
    __shared__ uint32_t lstart[NB];  // exclusive starts in sorted[]
    __shared__ uint32_t lcur[NB];    // placement cursors
    __shared__ uint32_t gcur[NB];    // persistent global cursors
    __shared__ uint2 sorted[SB];     // 32 KB
    __shared__ uint32_t s_nsb;

    int tid = threadIdx.x, b = blockIdx.x;
    if (tid < NB) gcur[tid] = boff[tid] + base[b * NB + tid];

    for (int sb = 0; sb < NSB; ++sb) {
        if (tid < NB) bh[tid] = 0;
        __syncthreads();

        int i0 = b * (HPB / 4) + sb * SBF4 + tid;
        int i1 = i0 + 512;
        float4 xa = x4[i0], xb = x4[i1];
        float4 ya = y4[i0], yb = y4[i1];
        float4 va = v4[i0], vb = v4[i1];
        float xs[8] = {xa.x, xa.y, xa.z, xa.w, xb.x, xb.y, xb.z, xb.w};
        float ys[8] = {ya.x, ya.y, ya.z, ya.w, yb.x, yb.y, yb.z, yb.w};
        float vs[8] = {va.x, va.y, va.z, va.w, vb.x, vb.y, vb.z, vb.w};
        uint32_t pk[8];
        bool ok[8];
#pragma unroll
        for (int j = 0; j < 8; ++j) {
            float fy = floorf((ys[j] + 3.0f) / INV_D);
            ok[j] = (fy >= 0.0f && fy < 1024.0f);
            uint32_t yi = ok[j] ? (uint32_t)(int)fy : 0u;
            float fx = floorf((xs[j] + 3.0f) / INV_D);
            bool xok = (fx >= 0.0f && fx < 1024.0f);
            pk[j] = (yi << 10) | (xok ? (uint32_t)(int)fx : 0u);
            if (!xok) vs[j] = 0.0f;
            if (ok[j]) atomicAdd(&bh[yi >> 3], 1u);
        }
        __syncthreads();

        // inclusive scan of bh (128 wide, Hillis-Steele)
        if (tid < NB) ps[tid] = bh[tid];
        __syncthreads();
        for (int off = 1; off < NB; off <<= 1) {
            uint32_t add = 0;
            if (tid < NB && tid >= off) add = ps[tid - off];
            __syncthreads();
            if (tid < NB) ps[tid] += add;
            __syncthreads();
        }
        if (tid < NB) {
            uint32_t e = ps[tid] - bh[tid];
            lstart[tid] = e;
            lcur[tid] = e;
        }
        if (tid == NB - 1) s_nsb = ps[tid];
        __syncthreads();

        // place into LDS sorted buffer
#pragma unroll
        for (int j = 0; j < 8; ++j) {
            if (ok[j]) {
                uint32_t s = atomicAdd(&lcur[pk[j] >> 13], 1u);
                sorted[s] = make_uint2(pk[j], __float_as_uint(vs[j]));
            }
        }
        __syncthreads();

        // coalesced copy-out: consecutive i -> consecutive global addrs
        uint32_t nsb = s_nsb;
        for (uint32_t i = (uint32_t)tid; i < nsb; i += 512) {
            uint2 pr = sorted[i];
            uint32_t t = pr.x >> 13;
            pairs[gcur[t] + (i - lstart[t])] = pr;
        }
        __syncthreads();
        if (tid < NB) gcur[tid] += bh[tid];
        __syncthreads();
    }
}

// ---- pass 2: per-chunk LDS band histogram (8x1024, 32 KB) --------------
__global__ __launch_bounds__(512) void k_accum(const uint2* __restrict__ pairs,
                                               const uint32_t* __restrict__ boff,
                                               const uint32_t* __restrict__ total,
                                               const uint32_t* __restrict__ cbase,
                                               float* __restrict__ partials) {
    __shared__ float hist[HISTW];
    int c = blockIdx.x, tid = threadIdx.x;
    uint32_t nch = cbase[NB];
    if ((uint32_t)c >= nch) return;
    int lo = 0, hi = NB - 1;
    while (lo < hi) {
        int mid = (lo + hi + 1) >> 1;
        if (cbase[mid] <= (uint32_t)c) lo = mid; else hi = mid - 1;
    }
    int t = lo;
    uint32_t k = (uint32_t)c - cbase[t];
    uint32_t st = boff[t] + k * (uint32_t)CHUNK;       // even
    uint32_t en = boff[t] + total[t];
    uint32_t en2 = st + (uint32_t)CHUNK;
    if (en2 < en) en = en2;
    for (int i = tid; i < HISTW; i += 512) hist[i] = 0.0f;
    __syncthreads();
    uint32_t npairs = (en > st) ? (en - st) : 0u;
    uint32_t nv = npairs >> 1;                          // uint4 = 2 pairs
    const uint4* p4 = (const uint4*)(pairs + st);
    uint32_t i = (uint32_t)tid;
    // 2x ILP: two independent uint4 loads in flight per iteration
    for (; i + 512u < nv; i += 1024u) {
        uint4 a = p4[i];
        uint4 b2 = p4[i + 512u];
        atomicAdd(&hist[((a.x >> 10) & 7u) * 1024 + (a.x & 1023u)], __uint_as_float(a.y));
        atomicAdd(&hist[((a.z >> 10) & 7u) * 1024 + (a.z & 1023u)], __uint_as_float(a.w));
        atomicAdd(&hist[((b2.x >> 10) & 7u) * 1024 + (b2.x & 1023u)], __uint_as_float(b2.y));
        atomicAdd(&hist[((b2.z >> 10) & 7u) * 1024 + (b2.z & 1023u)], __uint_as_float(b2.w));
    }
    for (; i < nv; i += 512u) {
        uint4 a = p4[i];
        atomicAdd(&hist[((a.x >> 10) & 7u) * 1024 + (a.x & 1023u)], __uint_as_float(a.y));
        atomicAdd(&hist[((a.z >> 10) & 7u) * 1024 + (a.z & 1023u)], __uint_as_float(a.w));
    }
    if ((npairs & 1u) && tid == 0) {
        uint2 pr = pairs[en - 1];
        atomicAdd(&hist[((pr.x >> 10) & 7u) * 1024 + (pr.x & 1023u)], __uint_as_float(pr.y));
    }
    __syncthreads();
    float4* dst = (float4*)(partials + (size_t)c * HISTW);
    const float4* src = (const float4*)hist;
    for (int i2 = tid; i2 < HISTW / 4; i2 += 512) dst[i2] = src[i2];
}

// ---- pass 3: reduce partials, write final image (every pixel once) -----
__global__ __launch_bounds__(256) void k_reduce(const float* __restrict__ partials,
                                                const uint32_t* __restrict__ cbase,
                                                float* __restrict__ out) {
    int t = blockIdx.x, tid = threadIdx.x;
    uint32_t c0 = cbase[t], c1 = cbase[t + 1];
    float4* o4 = (float4*)(out + (size_t)t * HISTW);
    for (int i = tid; i < HISTW / 4; i += 256) {
        float4 s = make_float4(0.f, 0.f, 0.f, 0.f);
        for (uint32_t c = c0; c < c1; ++c) {
            float4 p = ((const float4*)(partials + (size_t)c * HISTW))[i];
            s.x += p.x; s.y += p.y; s.z += p.z; s.w += p.w;
        }
        o4[i] = s;
    }
}

// ---- fallback: direct-atomic version (known-correct) -------------------
__global__ __launch_bounds__(256) void k_naive(const float4* __restrict__ x4,
                                               const float4* __restrict__ y4,
                                               const float4* __restrict__ v4,
                                               float* __restrict__ out,
                                               int n_chunks) {
    int stride = gridDim.x * blockDim.x;
    for (int i = blockIdx.x * blockDim.x + threadIdx.x; i < n_chunks; i += stride) {
        float4 xv = x4[i];
        float4 yv = y4[i];
        float4 vv = v4[i];
        float xs[4] = {xv.x, xv.y, xv.z, xv.w};
        float ys[4] = {yv.x, yv.y, yv.z, yv.w};
        float vs[4] = {vv.x, vv.y, vv.z, vv.w};
#pragma unroll
        for (int j = 0; j < 4; ++j) {
            uint32_t p = pix_of(xs[j], ys[j]);
            if (p != 0xFFFFFFFFu) atomicAdd(&out[(p >> 10) * SW + (p & 1023u)], vs[j]);
        }
    }
}

extern "C" void kernel_launch(void* const* d_in, const int* in_sizes, int n_in,
                              void* d_out, int out_size, void* d_ws, size_t ws_size,
                              hipStream_t stream) {
    const float* x = (const float*)d_in[0];
    const float* y = (const float*)d_in[1];
    const float* v = (const float*)d_in[2];
    float* out = (float*)d_out;
    int n = in_sizes[0];

    if (n == N_HITS && ws_size >= WS_BYTES) {
        uint32_t* w = (uint32_t*)d_ws;
        uint32_t* cnt   = w + OFS_CNT;
        uint32_t* base  = w + OFS_BASE;
        uint32_t* total = w + OFS_TOTAL;
        uint32_t* boff  = w + OFS_BOFF;
        uint32_t* cbase = w + OFS_CBASE;
        uint2*    pairs = (uint2*)(w + OFS_PAIRS);
        float*    parts = (float*)(w + OFS_PART);

        k_count<<<B1, 256, 0, stream>>>((const float4*)y, cnt);
        k_scan_blocks<<<NB, 256, 0, stream>>>(cnt, base, total);
        k_scan_bands<<<1, 64, 0, stream>>>(total, boff, cbase);
        k_scatter<<<B1, 512, 0, stream>>>((const float4*)x, (const float4*)y,
                                          (const float4*)v, base, boff, pairs);
        k_accum<<<MAXCH, 512, 0, stream>>>(pairs, boff, total, cbase, parts);
        k_reduce<<<NB, 256, 0, stream>>>(parts, cbase, out);
    } else {
        hipMemsetAsync(out, 0, (size_t)out_size * sizeof(float), stream);
        k_naive<<<4096, 256, 0, stream>>>((const float4*)x, (const float4*)y,
                                          (const float4*)v, out, n / 4);
    }
}

// Round 6
// 242.223 us; speedup vs baseline: 1.5880x; 1.1444x over previous
//
#include <hip/hip_runtime.h>
#include <stdint.h>

#define SW 1024
#define NB 256                   // 256 bands x 4 rows
#define N_HITS (1 << 24)
#define B1 1024                  // blocks for count/scatter
#define HPB (N_HITS / B1)        // 16384 hits per block
#define RND (HPB / 1024)         // 16 rounds (256 thr * 4) for k_count
#define SB 4096                  // hits per scatter sub-batch
#define SBF4 (SB / 4)            // 1024 float4 per sub-batch
#define NSB (HPB / SB)           // 4 sub-batches
#define CHUNK 32768              // hits per accumulation chunk
#define MAXCH (NB + N_HITS / CHUNK)   // 256 + 512 = 768
#define HISTW (4 * 1024)         // 4 rows x 1024 cols = 16 KB

// ws layout (u32 words). cnt and base share one array (in-place scan) so the
// total stays at 147.9 MB -- under the 151 MB proven available in round 2.
#define OFS_CB    0u                                 // B1*NB counts->bases
#define OFS_TOTAL (OFS_CB + (uint32_t)B1 * NB)       // 262144
#define OFS_BOFF  (OFS_TOTAL + NB)                   // 262400
#define OFS_CBASE (OFS_BOFF + NB + 1)                // 262657
#define OFS_PAIRS 262916u                            // mult of 4 -> 16B aligned
#define PAIR_CAP  ((uint32_t)N_HITS + 256u)          // + band-padding slack
#define OFS_PART  (OFS_PAIRS + 2u * PAIR_CAP)        // 33817860 (mult of 4)
#define WS_WORDS  (OFS_PART + (uint32_t)MAXCH * HISTW)
#define WS_BYTES  ((size_t)WS_WORDS * 4u)            // 147,854,352 B

#define INV_D 0.005859375f       // 6/1024, exact

__device__ __forceinline__ uint32_t pix_of(float x, float y) {
    float fx = floorf((x + 3.0f) / INV_D);
    float fy = floorf((y + 3.0f) / INV_D);
    if (fx >= 0.0f && fx < 1024.0f && fy >= 0.0f && fy < 1024.0f) {
        return ((uint32_t)(int)fy << 10) | (uint32_t)(int)fx;
    }
    return 0xFFFFFFFFu;
}

// ---- pass 1a: per-(block,band) counts from y only ----------------------
__global__ __launch_bounds__(256) void k_count(const float4* __restrict__ y4,
                                               uint32_t* __restrict__ cnt) {
    __shared__ uint32_t lcnt[4 * NB];   // per-wave counters
    int tid = threadIdx.x, b = blockIdx.x;
    int wave = tid >> 6;
    lcnt[tid] = 0; lcnt[tid + 256] = 0; lcnt[tid + 512] = 0; lcnt[tid + 768] = 0;
    __syncthreads();
    int base4 = b * (HPB / 4);
#pragma unroll
    for (int r = 0; r < RND; ++r) {
        float4 yv = y4[base4 + r * 256 + tid];
        float ys[4] = {yv.x, yv.y, yv.z, yv.w};
#pragma unroll
        for (int j = 0; j < 4; ++j) {
            float fy = floorf((ys[j] + 3.0f) / INV_D);
            if (fy >= 0.0f && fy < 1024.0f) {
                atomicAdd(&lcnt[wave * NB + ((int)fy >> 2)], 1u);
            }
        }
    }
    __syncthreads();
    cnt[b * NB + tid] = lcnt[tid] + lcnt[NB + tid] + lcnt[2 * NB + tid] + lcnt[3 * NB + tid];
}

// ---- pass 1b: per-band exclusive scan over blocks (IN PLACE) -----------
__global__ __launch_bounds__(256) void k_scan_blocks(uint32_t* __restrict__ cb,
                                                     uint32_t* __restrict__ total) {
    __shared__ uint32_t s[256];
    __shared__ uint32_t carry;
    int t = blockIdx.x, tid = threadIdx.x;
    if (tid == 0) carry = 0;
    __syncthreads();
    for (int r = 0; r < B1 / 256; ++r) {
        int b = r * 256 + tid;
        uint32_t v = cb[b * NB + t];
        s[tid] = v;
        __syncthreads();
        for (int off = 1; off < 256; off <<= 1) {
            uint32_t add = (tid >= off) ? s[tid - off] : 0u;
            __syncthreads();
            s[tid] += add;
            __syncthreads();
        }
        uint32_t incl = s[tid];
        uint32_t c = carry;
        cb[b * NB + t] = c + incl - v;          // exclusive base, in place
        __syncthreads();
        if (tid == 255) carry = c + incl;
        __syncthreads();
    }
    if (tid == 0) total[t] = carry;
}

// ---- pass 1b2: band offsets (16B-aligned starts) + chunk bases ---------
__global__ __launch_bounds__(64) void k_scan_bands(const uint32_t* __restrict__ total,
                                                   uint32_t* __restrict__ boff,
                                                   uint32_t* __restrict__ cbase) {
    if (threadIdx.x == 0 && blockIdx.x == 0) {
        uint32_t acc = 0, cacc = 0;
        for (int i = 0; i < NB; ++i) {
            boff[i] = acc;
            cbase[i] = cacc;
            uint32_t v = total[i];
            acc += v;
            acc = (acc + 1u) & ~1u;
            uint32_t cc = (v + CHUNK - 1) / CHUNK;
            cacc += (cc == 0) ? 1u : cc;
        }
        boff[NB] = acc;
        cbase[NB] = cacc;
    }
}

// ---- pass 1c: LDS counting-sort scatter --------------------------------
__global__ __launch_bounds__(512) void k_scatter(const float4* __restrict__ x4,
                                                 const float4* __restrict__ y4,
                                                 const float4* __restrict__ v4,
                                                 const uint32_t* __restrict__ base,
                                                 const uint32_t* __restrict__ boff,
                                                 uint2* __restrict__ pairs) {
    __shared__ uint32_t bh[NB];      // sub-batch band counts
    __shared__ uint32_t ps[NB];      // scan scratch
    __shared__ uint32_t lstart[NB];  // exclusive starts in sorted[]
    __shared__ uint32_t lcur[NB];    // placement cursors
    __shared__ uint32_t gcur[NB];    // persistent global cursors
    __shared__ uint2 sorted[SB];     // 32 KB
    __shared__ uint32_t s_nsb;

    int tid = threadIdx.x, b = blockIdx.x;
    if (tid < NB) gcur[tid] = boff[tid] + base[b * NB + tid];

    for (int sb = 0; sb < NSB; ++sb) {
        if (tid < NB) bh[tid] = 0;
        __syncthreads();

        int i0 = b * (HPB / 4) + sb * SBF4 + tid;
        int i1 = i0 + 512;
        float4 xa = x4[i0], xb = x4[i1];
        float4 ya = y4[i0], yb = y4[i1];
        float4 va = v4[i0], vb = v4[i1];
        float xs[8] = {xa.x, xa.y, xa.z, xa.w, xb.x, xb.y, xb.z, xb.w};
        float ys[8] = {ya.x, ya.y, ya.z, ya.w, yb.x, yb.y, yb.z, yb.w};
        float vs[8] = {va.x, va.y, va.z, va.w, vb.x, vb.y, vb.z, vb.w};
        uint32_t pk[8];
        bool ok[8];
#pragma unroll
        for (int j = 0; j < 8; ++j) {
            float fy = floorf((ys[j] + 3.0f) / INV_D);
            ok[j] = (fy >= 0.0f && fy < 1024.0f);
            uint32_t yi = ok[j] ? (uint32_t)(int)fy : 0u;
            float fx = floorf((xs[j] + 3.0f) / INV_D);
            bool xok = (fx >= 0.0f && fx < 1024.0f);
            pk[j] = (yi << 10) | (xok ? (uint32_t)(int)fx : 0u);
            if (!xok) vs[j] = 0.0f;
            if (ok[j]) atomicAdd(&bh[yi >> 2], 1u);
        }
        __syncthreads();

        // inclusive scan of bh (256 wide, Hillis-Steele)
        if (tid < NB) ps[tid] = bh[tid];
        __syncthreads();
        for (int off = 1; off < NB; off <<= 1) {
            uint32_t add = 0;
            if (tid < NB && tid >= off) add = ps[tid - off];
            __syncthreads();
            if (tid < NB) ps[tid] += add;
            __syncthreads();
        }
        if (tid < NB) {
            uint32_t e = ps[tid] - bh[tid];
            lstart[tid] = e;
            lcur[tid] = e;
        }
        if (tid == NB - 1) s_nsb = ps[tid];
        __syncthreads();

        // place into LDS sorted buffer
#pragma unroll
        for (int j = 0; j < 8; ++j) {
            if (ok[j]) {
                uint32_t s = atomicAdd(&lcur[pk[j] >> 12], 1u);
                sorted[s] = make_uint2(pk[j], __float_as_uint(vs[j]));
            }
        }
        __syncthreads();

        // coalesced copy-out: consecutive i -> consecutive global addrs
        uint32_t nsb = s_nsb;
        for (uint32_t i = (uint32_t)tid; i < nsb; i += 512) {
            uint2 pr = sorted[i];
            uint32_t t = pr.x >> 12;
            pairs[gcur[t] + (i - lstart[t])] = pr;
        }
        __syncthreads();
        if (tid < NB) gcur[tid] += bh[tid];
        __syncthreads();
    }
}

// ---- pass 2: per-chunk LDS band histogram (4x1024, 16 KB) --------------
__global__ __launch_bounds__(512) void k_accum(const uint2* __restrict__ pairs,
                                               const uint32_t* __restrict__ boff,
                                               const uint32_t* __restrict__ total,
                                               const uint32_t* __restrict__ cbase,
                                               float* __restrict__ partials) {
    __shared__ float hist[HISTW];
    int c = blockIdx.x, tid = threadIdx.x;
    uint32_t nch = cbase[NB];
    if ((uint32_t)c >= nch) return;
    int lo = 0, hi = NB - 1;
    while (lo < hi) {
        int mid = (lo + hi + 1) >> 1;
        if (cbase[mid] <= (uint32_t)c) lo = mid; else hi = mid - 1;
    }
    int t = lo;
    uint32_t k = (uint32_t)c - cbase[t];
    uint32_t st = boff[t] + k * (uint32_t)CHUNK;       // even
    uint32_t en = boff[t] + total[t];
    uint32_t en2 = st + (uint32_t)CHUNK;
    if (en2 < en) en = en2;
    for (int i = tid; i < HISTW; i += 512) hist[i] = 0.0f;
    __syncthreads();
    uint32_t npairs = (en > st) ? (en - st) : 0u;
    uint32_t nv = npairs >> 1;                          // uint4 = 2 pairs
    const uint4* p4 = (const uint4*)(pairs + st);
    uint32_t i = (uint32_t)tid;
    // 4x ILP: four independent uint4 loads in flight per iteration
    for (; i + 1536u < nv; i += 2048u) {
        uint4 a = p4[i];
        uint4 b2 = p4[i + 512u];
        uint4 c2 = p4[i + 1024u];
        uint4 d2 = p4[i + 1536u];
        atomicAdd(&hist[((a.x >> 10) & 3u) * 1024 + (a.x & 1023u)], __uint_as_float(a.y));
        atomicAdd(&hist[((a.z >> 10) & 3u) * 1024 + (a.z & 1023u)], __uint_as_float(a.w));
        atomicAdd(&hist[((b2.x >> 10) & 3u) * 1024 + (b2.x & 1023u)], __uint_as_float(b2.y));
        atomicAdd(&hist[((b2.z >> 10) & 3u) * 1024 + (b2.z & 1023u)], __uint_as_float(b2.w));
        atomicAdd(&hist[((c2.x >> 10) & 3u) * 1024 + (c2.x & 1023u)], __uint_as_float(c2.y));
        atomicAdd(&hist[((c2.z >> 10) & 3u) * 1024 + (c2.z & 1023u)], __uint_as_float(c2.w));
        atomicAdd(&hist[((d2.x >> 10) & 3u) * 1024 + (d2.x & 1023u)], __uint_as_float(d2.y));
        atomicAdd(&hist[((d2.z >> 10) & 3u) * 1024 + (d2.z & 1023u)], __uint_as_float(d2.w));
    }
    for (; i < nv; i += 512u) {
        uint4 a = p4[i];
        atomicAdd(&hist[((a.x >> 10) & 3u) * 1024 + (a.x & 1023u)], __uint_as_float(a.y));
        atomicAdd(&hist[((a.z >> 10) & 3u) * 1024 + (a.z & 1023u)], __uint_as_float(a.w));
    }
    if ((npairs & 1u) && tid == 0) {
        uint2 pr = pairs[en - 1];
        atomicAdd(&hist[((pr.x >> 10) & 3u) * 1024 + (pr.x & 1023u)], __uint_as_float(pr.y));
    }
    __syncthreads();
    float4* dst = (float4*)(partials + (size_t)c * HISTW);
    const float4* src = (const float4*)hist;
    for (int i2 = tid; i2 < HISTW / 4; i2 += 512) dst[i2] = src[i2];
}

// ---- pass 3: reduce partials, write final image (every pixel once) -----
__global__ __launch_bounds__(256) void k_reduce(const float* __restrict__ partials,
                                                const uint32_t* __restrict__ cbase,
                                                float* __restrict__ out) {
    int t = blockIdx.x, tid = threadIdx.x;
    uint32_t c0 = cbase[t], c1 = cbase[t + 1];
    float4* o4 = (float4*)(out + (size_t)t * HISTW);
    for (int i = tid; i < HISTW / 4; i += 256) {
        float4 s = make_float4(0.f, 0.f, 0.f, 0.f);
        for (uint32_t c = c0; c < c1; ++c) {
            float4 p = ((const float4*)(partials + (size_t)c * HISTW))[i];
            s.x += p.x; s.y += p.y; s.z += p.z; s.w += p.w;
        }
        o4[i] = s;
    }
}

// ---- fallback: direct-atomic version (known-correct) -------------------
__global__ __launch_bounds__(256) void k_naive(const float4* __restrict__ x4,
                                               const float4* __restrict__ y4,
                                               const float4* __restrict__ v4,
                                               float* __restrict__ out,
                                               int n_chunks) {
    int stride = gridDim.x * blockDim.x;
    for (int i = blockIdx.x * blockDim.x + threadIdx.x; i < n_chunks; i += stride) {
        float4 xv = x4[i];
        float4 yv = y4[i];
        float4 vv = v4[i];
        float xs[4] = {xv.x, xv.y, xv.z, xv.w};
        float ys[4] = {yv.x, yv.y, yv.z, yv.w};
        float vs[4] = {vv.x, vv.y, vv.z, vv.w};
#pragma unroll
        for (int j = 0; j < 4; ++j) {
            uint32_t p = pix_of(xs[j], ys[j]);
            if (p != 0xFFFFFFFFu) atomicAdd(&out[(p >> 10) * SW + (p & 1023u)], vs[j]);
        }
    }
}

extern "C" void kernel_launch(void* const* d_in, const int* in_sizes, int n_in,
                              void* d_out, int out_size, void* d_ws, size_t ws_size,
                              hipStream_t stream) {
    const float* x = (const float*)d_in[0];
    const float* y = (const float*)d_in[1];
    const float* v = (const float*)d_in[2];
    float* out = (float*)d_out;
    int n = in_sizes[0];

    if (n == N_HITS && ws_size >= WS_BYTES) {
        uint32_t* w = (uint32_t*)d_ws;
        uint32_t* cb    = w + OFS_CB;      // counts, then in-place bases
        uint32_t* total = w + OFS_TOTAL;
        uint32_t* boff  = w + OFS_BOFF;
        uint32_t* cbase = w + OFS_CBASE;
        uint2*    pairs = (uint2*)(w + OFS_PAIRS);
        float*    parts = (float*)(w + OFS_PART);

        k_count<<<B1, 256, 0, stream>>>((const float4*)y, cb);
        k_scan_blocks<<<NB, 256, 0, stream>>>(cb, total);
        k_scan_bands<<<1, 64, 0, stream>>>(total, boff, cbase);
        k_scatter<<<B1, 512, 0, stream>>>((const float4*)x, (const float4*)y,
                                          (const float4*)v, cb, boff, pairs);
        k_accum<<<MAXCH, 512, 0, stream>>>(pairs, boff, total, cbase, parts);
        k_reduce<<<NB, 256, 0, stream>>>(parts, cbase, out);
    } else {
        hipMemsetAsync(out, 0, (size_t)out_size * sizeof(float), stream);
        k_naive<<<4096, 256, 0, stream>>>((const float4*)x, (const float4*)y,
                                          (const float4*)v, out, n / 4);
    }
}